// Round 1
// baseline (192.527 us; speedup 1.0000x reference)
//
#include <hip/hip_runtime.h>
#include <hip/hip_cooperative_groups.h>

namespace cg = cooperative_groups;

#define MAX_POINTS 32
#define C_OUT 64
#define EPS 1e-5f

// 15 moments: [0..3] sum x,y,z,w; [4..13] xx,xy,xz,xw,yy,yz,yw,zz,zw,ww; [14] count
#define NMOM 15
#define TPB 1024
#define NWAVE (TPB / 64)
#define VPB 157          // voxels per block: ceil(40000 / 256)

__global__ __launch_bounds__(TPB) void vfe_fused(
    const float* __restrict__ x, const int* __restrict__ vnp,
    const float* __restrict__ W, const float* __restrict__ b,
    const float* __restrict__ gamma, const float* __restrict__ beta,
    float* __restrict__ wsp, float* __restrict__ out, int M)
{
    __shared__ float4 sx[VPB * MAX_POINTS];   // 80,384 B: this block's x slice
    __shared__ float  bl[NWAVE][NMOM];        // per-wave partials
    __shared__ float  red[NMOM][16];          // cross-block reduction scratch
    __shared__ float  smom[NMOM];             // final global moments

    const int tid  = threadIdx.x;
    const int lane = tid & 63;
    const int wid  = tid >> 6;
    const int base = blockIdx.x * VPB;
    const int nvox = max(0, min(VPB, M - base));
    const int slots = nvox * MAX_POINTS;

    // ---------------- Phase 1: stage x slice to LDS + 15-moment partials ----
    float a[NMOM];
    #pragma unroll
    for (int i = 0; i < NMOM; ++i) a[i] = 0.f;

    const float4* __restrict__ xq = (const float4*)x + (size_t)base * MAX_POINTS;
    for (int i = tid; i < slots; i += TPB) {
        float4 q = xq[i];                      // coalesced 16B/lane
        sx[i] = q;                             // stage raw (phase 2 masks by n)
        const int n = vnp[base + (i >> 5)];    // L1-cached, 32 lanes share
        if ((i & 31) < n) {
            a[14] += 1.f;
        } else {
            q = make_float4(0.f, 0.f, 0.f, 0.f);
        }
        a[0] += q.x; a[1] += q.y; a[2] += q.z; a[3] += q.w;
        a[4]  = fmaf(q.x, q.x, a[4]);
        a[5]  = fmaf(q.x, q.y, a[5]);
        a[6]  = fmaf(q.x, q.z, a[6]);
        a[7]  = fmaf(q.x, q.w, a[7]);
        a[8]  = fmaf(q.y, q.y, a[8]);
        a[9]  = fmaf(q.y, q.z, a[9]);
        a[10] = fmaf(q.y, q.w, a[10]);
        a[11] = fmaf(q.z, q.z, a[11]);
        a[12] = fmaf(q.z, q.w, a[12]);
        a[13] = fmaf(q.w, q.w, a[13]);
    }

    // wave reduce (64 lanes)
    #pragma unroll
    for (int i = 0; i < NMOM; ++i) {
        float v = a[i];
        #pragma unroll
        for (int off = 32; off > 0; off >>= 1)
            v += __shfl_down(v, off, 64);
        a[i] = v;
    }
    if (lane == 0) {
        #pragma unroll
        for (int i = 0; i < NMOM; ++i) bl[wid][i] = a[i];
    }
    __syncthreads();
    // one per-block partial per moment -> global, NO atomics
    if (tid < NMOM) {
        float s = 0.f;
        #pragma unroll
        for (int w = 0; w < NWAVE; ++w) s += bl[w][tid];
        wsp[blockIdx.x * NMOM + tid] = s;
    }
    __threadfence();
    cg::this_grid().sync();

    // ---------------- Cross-block moment reduction (each block, own copy) --
    const int nb = gridDim.x;
    if (tid < NMOM * 16) {
        const int mom = tid >> 4;
        const int g   = tid & 15;
        float s = 0.f;
        for (int bb = g; bb < nb; bb += 16) s += wsp[bb * NMOM + mom];
        red[mom][g] = s;
    }
    __syncthreads();
    if (tid < NMOM) {
        float s = 0.f;
        #pragma unroll
        for (int g = 0; g < 16; ++g) s += red[tid][g];
        smom[tid] = s;
    }
    __syncthreads();

    // ---------------- Per-channel BN affine (lane = output channel) --------
    const float4 w4  = ((const float4*)W)[lane];
    const float bias = b[lane];
    const float cnt  = smom[14];
    const float nv   = fmaxf(cnt, 1.0f);
    const float wdots = w4.x*smom[0] + w4.y*smom[1] + w4.z*smom[2] + w4.w*smom[3];
    const float S    = wdots + cnt * bias;
    const float mu   = S / nv;
    const float q2 = smom[4]*w4.x*w4.x + smom[8]*w4.y*w4.y + smom[11]*w4.z*w4.z
                   + smom[13]*w4.w*w4.w
                   + 2.f*(smom[5]*w4.x*w4.y + smom[6]*w4.x*w4.z + smom[7]*w4.x*w4.w
                        + smom[9]*w4.y*w4.z + smom[10]*w4.y*w4.w + smom[12]*w4.z*w4.w);
    const float SS  = q2 + 2.f*bias*wdots + cnt*bias*bias;
    const float var = fmaxf(SS / nv - mu * mu, 0.f);
    const float A   = gamma[lane] * rsqrtf(var + EPS);
    const float B   = fmaf(-mu, A, beta[lane]);

    // ---------------- Phase 2: outputs straight from staged LDS ------------
    for (int mv = wid; mv < nvox; mv += NWAVE) {
        const int m = base + mv;
        const int n = vnp[m];                    // wave-uniform
        const float4* __restrict__ q = &sx[mv * MAX_POINTS];
        float acc = 0.f;
        #pragma unroll 4
        for (int p = 0; p < n; ++p) {
            const float4 pt = q[p];              // LDS same-addr broadcast
            const float h = fmaf(pt.x, w4.x, fmaf(pt.y, w4.y,
                            fmaf(pt.z, w4.z, fmaf(pt.w, w4.w, bias))));
            acc += fmaxf(fmaf(h, A, B), 0.f);
        }
        out[(size_t)m * C_OUT + lane] = acc / fmaxf((float)n, 1.0f);
    }
}

extern "C" void kernel_launch(void* const* d_in, const int* in_sizes, int n_in,
                              void* d_out, int out_size, void* d_ws, size_t ws_size,
                              hipStream_t stream) {
    const float* x     = (const float*)d_in[0];
    const int*   vnp   = (const int*)  d_in[1];
    const float* W     = (const float*)d_in[2];
    const float* b     = (const float*)d_in[3];
    const float* gamma = (const float*)d_in[4];
    const float* beta  = (const float*)d_in[5];
    float* out = (float*)d_out;
    float* wsp = (float*)d_ws;
    int M = in_sizes[1];                         // 40000 voxels

    const int nblk = (M + VPB - 1) / VPB;        // 256 blocks -> 1/CU, co-resident
    void* args[] = {(void*)&x, (void*)&vnp, (void*)&W, (void*)&b,
                    (void*)&gamma, (void*)&beta, (void*)&wsp, (void*)&out, (void*)&M};
    hipLaunchCooperativeKernel((void*)vfe_fused, dim3(nblk), dim3(TPB),
                               args, 0, stream);
}

// Round 2
// 101.633 us; speedup vs baseline: 1.8943x; 1.8943x over previous
//
#include <hip/hip_runtime.h>

#define MAX_POINTS 32
#define C_OUT 64
#define EPS 1e-5f

// 15 moments: [0..3] sum x,y,z,w; [4..13] xx,xy,xz,xw,yy,yz,yw,zz,zw,ww; [14] count
#define NMOM 15

#define K1_BLOCKS 512
#define K1_TPB 1024
#define K1_NWAVE (K1_TPB / 64)

#define K2_TPB 512
#define K2_NWAVE (K2_TPB / 64)
#define K2_VOX 64            // voxels per block (32 KB LDS)

// ---------------- Kernel 1: 15-moment reduction, per-block partials ---------
__global__ __launch_bounds__(K1_TPB) void vfe_stats(
    const float* __restrict__ x, const int* __restrict__ vnp,
    float* __restrict__ wsp, int M)
{
    const int tid    = blockIdx.x * K1_TPB + threadIdx.x;
    const int stride = K1_BLOCKS * K1_TPB;
    const int total  = M * MAX_POINTS;           // flat float4 slots

    float a[NMOM];
    #pragma unroll
    for (int i = 0; i < NMOM; ++i) a[i] = 0.f;

    const float4* __restrict__ xq = (const float4*)x;
    for (int i = tid; i < total; i += stride) {
        float4 q = xq[i];                        // unconditional: issues with vnp load
        const int n = vnp[i >> 5];               // L1-cached, 32 lanes share
        const bool valid = (i & 31) < n;
        if (valid) a[14] += 1.f;
        else       q = make_float4(0.f, 0.f, 0.f, 0.f);
        a[0] += q.x; a[1] += q.y; a[2] += q.z; a[3] += q.w;
        a[4]  = fmaf(q.x, q.x, a[4]);
        a[5]  = fmaf(q.x, q.y, a[5]);
        a[6]  = fmaf(q.x, q.z, a[6]);
        a[7]  = fmaf(q.x, q.w, a[7]);
        a[8]  = fmaf(q.y, q.y, a[8]);
        a[9]  = fmaf(q.y, q.z, a[9]);
        a[10] = fmaf(q.y, q.w, a[10]);
        a[11] = fmaf(q.z, q.z, a[11]);
        a[12] = fmaf(q.z, q.w, a[12]);
        a[13] = fmaf(q.w, q.w, a[13]);
    }

    // wave reduce (64 lanes)
    #pragma unroll
    for (int i = 0; i < NMOM; ++i) {
        float v = a[i];
        #pragma unroll
        for (int off = 32; off > 0; off >>= 1)
            v += __shfl_down(v, off, 64);
        a[i] = v;
    }

    __shared__ float bl[K1_NWAVE][NMOM];
    const int lane = threadIdx.x & 63;
    const int wid  = threadIdx.x >> 6;
    if (lane == 0) {
        #pragma unroll
        for (int i = 0; i < NMOM; ++i) bl[wid][i] = a[i];
    }
    __syncthreads();
    // moment-major partials: wsp[mom*K1_BLOCKS + blk] -> coalesced k2 reads
    if (threadIdx.x < NMOM) {
        float s = 0.f;
        #pragma unroll
        for (int w = 0; w < K1_NWAVE; ++w) s += bl[w][threadIdx.x];
        wsp[threadIdx.x * K1_BLOCKS + blockIdx.x] = s;
    }
}

// ---------------- Kernel 2: reduce partials + LDS-staged output -------------
__global__ __launch_bounds__(K2_TPB) void vfe_out(
    const float* __restrict__ x, const int* __restrict__ vnp,
    const float* __restrict__ W, const float* __restrict__ b,
    const float* __restrict__ gamma, const float* __restrict__ beta,
    const float* __restrict__ wsp, float* __restrict__ out, int M)
{
    __shared__ float4 sx[K2_VOX * MAX_POINTS];   // 32 KB: this block's voxels
    __shared__ float  smom[NMOM];

    const int lane = threadIdx.x & 63;           // output channel
    const int wid  = threadIdx.x >> 6;
    const int m0   = blockIdx.x * K2_VOX;
    const int nvox = max(0, min(K2_VOX, M - m0));

    // A) stage voxels (coalesced float4)
    const float4* __restrict__ xq = (const float4*)x + (size_t)m0 * MAX_POINTS;
    const int limit = nvox * MAX_POINTS;
    for (int t = threadIdx.x; t < limit; t += K2_TPB) sx[t] = xq[t];

    // B) reduce the 512 per-block partials for each moment (wave w: mom w, w+8)
    for (int mom = wid; mom < NMOM; mom += K2_NWAVE) {
        const float4* __restrict__ pp = (const float4*)(wsp + mom * K1_BLOCKS);
        const float4 v0 = pp[lane * 2];
        const float4 v1 = pp[lane * 2 + 1];
        float s = (v0.x + v0.y) + (v0.z + v0.w) + (v1.x + v1.y) + (v1.z + v1.w);
        #pragma unroll
        for (int off = 32; off > 0; off >>= 1)
            s += __shfl_down(s, off, 64);
        if (lane == 0) smom[mom] = s;
    }
    __syncthreads();

    // C) per-channel BN affine from moments (lane = channel)
    const float4 w4  = ((const float4*)W)[lane];
    const float bias = b[lane];
    const float cnt  = smom[14];
    const float nv   = fmaxf(cnt, 1.0f);
    const float wdots = w4.x*smom[0] + w4.y*smom[1] + w4.z*smom[2] + w4.w*smom[3];
    const float S    = wdots + cnt * bias;
    const float mu   = S / nv;
    const float q2 = smom[4]*w4.x*w4.x + smom[8]*w4.y*w4.y + smom[11]*w4.z*w4.z
                   + smom[13]*w4.w*w4.w
                   + 2.f*(smom[5]*w4.x*w4.y + smom[6]*w4.x*w4.z + smom[7]*w4.x*w4.w
                        + smom[9]*w4.y*w4.z + smom[10]*w4.y*w4.w + smom[12]*w4.z*w4.w);
    const float SS  = q2 + 2.f*bias*wdots + cnt*bias*bias;
    const float var = fmaxf(SS / nv - mu * mu, 0.f);
    const float A   = gamma[lane] * rsqrtf(var + EPS);
    const float B   = fmaf(-mu, A, beta[lane]);

    // D) outputs straight from staged LDS (wave-uniform broadcast reads)
    for (int mv = wid; mv < nvox; mv += K2_NWAVE) {
        const int m = m0 + mv;
        const int n = vnp[m];                    // wave-uniform
        const float4* __restrict__ q = &sx[mv * MAX_POINTS];
        float acc = 0.f;
        #pragma unroll 4
        for (int p = 0; p < n; ++p) {
            const float4 pt = q[p];              // LDS same-addr broadcast
            const float h = fmaf(pt.x, w4.x, fmaf(pt.y, w4.y,
                            fmaf(pt.z, w4.z, fmaf(pt.w, w4.w, bias))));
            acc += fmaxf(fmaf(h, A, B), 0.f);
        }
        out[(size_t)m * C_OUT + lane] = acc / fmaxf((float)n, 1.0f);
    }
}

extern "C" void kernel_launch(void* const* d_in, const int* in_sizes, int n_in,
                              void* d_out, int out_size, void* d_ws, size_t ws_size,
                              hipStream_t stream) {
    const float* x     = (const float*)d_in[0];
    const int*   vnp   = (const int*)  d_in[1];
    const float* W     = (const float*)d_in[2];
    const float* b     = (const float*)d_in[3];
    const float* gamma = (const float*)d_in[4];
    const float* beta  = (const float*)d_in[5];
    float* out = (float*)d_out;
    float* wsp = (float*)d_ws;
    const int M = in_sizes[1];                   // 40000 voxels

    vfe_stats<<<K1_BLOCKS, K1_TPB, 0, stream>>>(x, vnp, wsp, M);
    const int nblk = (M + K2_VOX - 1) / K2_VOX;
    vfe_out<<<nblk, K2_TPB, 0, stream>>>(x, vnp, W, b, gamma, beta, wsp, out, M);
}